// Round 1
// baseline (38871.808 us; speedup 1.0000x reference)
//
#include <hip/hip_runtime.h>

#define H 2048
#define W 2048
#define NB 2
#define NL 3
#define NT 4       // 4x4 tile grid
#define HS 512     // tile step
#define OV2 32     // overlap/2
#define PH 128     // psf size
#define PC 64      // psf center

#define TY 64      // patch extent along y (lane-fast output dim)
#define TX 64      // patch extent along x
#define QC 16      // q-chunk (psf cols per stage)
#define RROWS (TX + QC - 1)   // 79 staged J rows
#define CCOLS (TY + PH - 1)   // 191 staged J cols
#define LSTRIDE 193           // odd stride -> 2-way LDS aliasing only (free)

// J[b][r][c] = target[b][0][r][2047-c]  (transposed rotated image == col-reversed original)
__global__ void build_J(const float* __restrict__ tgt, float* __restrict__ J) {
  int idx = blockIdx.x * 256 + threadIdx.x;
  if (idx >= NB * H * W) return;
  int c = idx & (W - 1);
  int r = (idx >> 11) & (H - 1);
  int b = idx >> 22;
  J[idx] = tgt[((size_t)(b * H) + r) * W + (W - 1 - c)];
}

// P2[l][i][j][q][p] = psfs[l][j*4+i][q][127-p]   (rot90'd, q-major for contiguous q-chunks)
__global__ void build_P2(const float* __restrict__ psfs, float* __restrict__ P2) {
  int idx = blockIdx.x * 256 + threadIdx.x;
  if (idx >= NL * NT * NT * PH * PH) return;
  int p = idx & 127;
  int q = (idx >> 7) & 127;
  int j = (idx >> 14) & 3;
  int i = (idx >> 16) & 3;
  int l = idx >> 18;
  P2[idx] = psfs[((size_t)(l * 16 + j * 4 + i) * PH + q) * PH + (PH - 1 - p)];
}

__global__ __launch_bounds__(256, 2)
void conv_kernel(const float* __restrict__ J, const float* __restrict__ P2,
                 float* __restrict__ out) {
  __shared__ float lds[RROWS * LSTRIDE];
  const int t  = threadIdx.x;
  const int gx = t >> 3;   // 0..31  -> x = x0 + gx + 32*m
  const int gy = t & 7;    // 0..7   -> y = y0 + 8*gy + k
  const int x0 = blockIdx.x * TX;
  const int y0 = blockIdx.y * TY;
  const int bl = blockIdx.z;
  const int b  = bl / NL;
  const int l  = bl - b * NL;
  const float* __restrict__ Jb = J + (size_t)b * H * W;

  // tiles intersecting this patch (1 or 2 per axis)
  const int tylo = (y0 > OV2 ? (y0 - OV2) : 0) / HS;
  const int tyhi = min(NT - 1, (y0 + TY - 1 + OV2) / HS);
  const int txlo = (x0 > OV2 ? (x0 - OV2) : 0) / HS;
  const int txhi = min(NT - 1, (x0 + TX - 1 + OV2) / HS);

  float facc[8][2] = {};
  float nacc[8][2] = {};

  for (int ti = tylo; ti <= tyhi; ++ti) {
    const int h0 = max(0, ti * HS - OV2);
    const int h1 = min(H, (ti + 1) * HS + OV2);
    for (int tj = txlo; tj <= txhi; ++tj) {
      const int w0 = max(0, tj * HS - OV2);
      const int w1 = min(W, (tj + 1) * HS + OV2);
      const float* __restrict__ Pb = P2 + (size_t)((l * NT + ti) * NT + tj) * (PH * PH);

      float pacc[8][2] = {};

      #pragma unroll 1
      for (int qc = 0; qc < PH; qc += QC) {
        __syncthreads();
        // stage J rows r = x + 64 - q  (clip to tile rect at stage time)
        const int rbase = x0 + PC - qc - (QC - 1);
        const int cbase = y0 - (PC - 1);
        for (int rr = (t >> 6); rr < RROWS; rr += 4) {
          const int rg = rbase + rr;
          const bool rok = (rg >= w0) && (rg < w1);
          const float* __restrict__ Jrow = Jb + (size_t)rg * W;
          for (int cc = (t & 63); cc < CCOLS; cc += 64) {
            const int cg = cbase + cc;
            float v = 0.0f;
            if (rok && cg >= h0 && cg < h1) v = Jrow[cg];
            lds[rr * LSTRIDE + cc] = v;
          }
        }
        __syncthreads();

        #pragma unroll 1
        for (int q = 0; q < QC; ++q) {
          const float* __restrict__ prow = Pb + (qc + q) * PH;  // wave-uniform
          const int r0 = (gx + (QC - 1 - q)) * LSTRIDE;
          const int r1 = r0 + 32 * LSTRIDE;
          const int cb = (gy << 3) + (PH - 1);
          float wa[8], wb[8];
          #pragma unroll
          for (int k = 0; k < 8; ++k) {
            wa[k] = lds[r0 + cb + k];
            wb[k] = lds[r1 + cb + k];
          }
          // sliding-window over p: 2 new LDS reads per 16 FMAs
          #pragma unroll 8
          for (int p = 0; p < PH - 1; ++p) {
            const float s = prow[p];
            #pragma unroll
            for (int k = 0; k < 8; ++k) {
              pacc[k][0] = fmaf(s, wa[k], pacc[k][0]);
              pacc[k][1] = fmaf(s, wb[k], pacc[k][1]);
            }
            #pragma unroll
            for (int k = 7; k > 0; --k) { wa[k] = wa[k - 1]; wb[k] = wb[k - 1]; }
            wa[0] = lds[r0 + cb - p - 1];
            wb[0] = lds[r1 + cb - p - 1];
          }
          {
            const float s = prow[PH - 1];
            #pragma unroll
            for (int k = 0; k < 8; ++k) {
              pacc[k][0] = fmaf(s, wa[k], pacc[k][0]);
              pacc[k][1] = fmaf(s, wb[k], pacc[k][1]);
            }
          }
        }
      }

      // window (separable gaussian) + tile-rect indicator, accumulate
      const int Sh = h1 - h0, Sw = w1 - w0;
      const float sig = 0.25f * (float)min(Sh, Sw);
      const float c2 = 0.5f / (sig * sig);
      const float stepy = (float)Sh / (float)(Sh - 1);
      const float stepx = (float)Sw / (float)(Sw - 1);
      float wy[8];
      #pragma unroll
      for (int k = 0; k < 8; ++k) {
        const int y = y0 + (gy << 3) + k;
        const float yv = -0.5f * (float)Sh + (float)(y - h0) * stepy;
        wy[k] = (y >= h0 && y < h1) ? __expf(-yv * yv * c2) : 0.0f;
      }
      float wx[2];
      #pragma unroll
      for (int m = 0; m < 2; ++m) {
        const int x = x0 + gx + 32 * m;
        const float xv = -0.5f * (float)Sw + (float)(x - w0) * stepx;
        wx[m] = (x >= w0 && x < w1) ? __expf(-xv * xv * c2) : 0.0f;
      }
      #pragma unroll
      for (int k = 0; k < 8; ++k) {
        #pragma unroll
        for (int m = 0; m < 2; ++m) {
          const float wf = wy[k] * wx[m];
          facc[k][m] = fmaf(wf, pacc[k][m], facc[k][m]);
          nacc[k][m] += wf;
        }
      }
    }
  }

  // rotated store: final[b,l, x, 2047-y]
  #pragma unroll
  for (int m = 0; m < 2; ++m) {
    const int x = x0 + gx + 32 * m;
    float* __restrict__ orow = out + ((size_t)(b * NL + l) * H + x) * W;
    #pragma unroll
    for (int k = 0; k < 8; ++k) {
      const int y = y0 + (gy << 3) + k;
      orow[W - 1 - y] = facc[k][m] / fmaxf(nacc[k][m], 1e-12f);
    }
  }
}

extern "C" void kernel_launch(void* const* d_in, const int* in_sizes, int n_in,
                              void* d_out, int out_size, void* d_ws, size_t ws_size,
                              hipStream_t stream) {
  const float* tgt  = (const float*)d_in[0];
  const float* psfs = (const float*)d_in[1];
  float* J  = (float*)d_ws;                    // NB*H*W floats (33.5 MB)
  float* P2 = J + (size_t)NB * H * W;          // 3*16*128*128 floats (3.1 MB)
  float* o  = (float*)d_out;

  build_J<<<dim3((NB * H * W + 255) / 256), dim3(256), 0, stream>>>(tgt, J);
  build_P2<<<dim3((NL * NT * NT * PH * PH + 255) / 256), dim3(256), 0, stream>>>(psfs, P2);
  conv_kernel<<<dim3(W / TX, H / TY, NB * NL), dim3(256), 0, stream>>>(J, P2, o);
}

// Round 2
// 25617.328 us; speedup vs baseline: 1.5174x; 1.5174x over previous
//
#include <hip/hip_runtime.h>

typedef float v2 __attribute__((ext_vector_type(2)));

#define H 2048
#define W 2048
#define NB 2
#define NL 3
#define NT 4       // 4x4 tile grid
#define HS 512     // tile step
#define OV2 32     // overlap/2
#define PH 128     // psf size
#define PC 64      // psf center

#define TY 64      // patch extent along y (lane-fast output dim)
#define TX 64      // patch extent along x
#define QC 8       // psf rows (q) per LDS stage
#define RROWS (TX + QC - 1)   // 71 staged J rows
#define CCOLS (TY + PH - 1)   // 191 staged J cols
#define LSTRIDE 194           // even stride: b64-aligned windows, banks (2gx+8gy+c)%32 -> uniform 4/bank
#define IMG_OFF 8             // left slack so the (dead) last-group prefetch stays in-bounds
#define IMG_FLOATS (RROWS * LSTRIDE)   // 13774
#define PSF_FLOATS (QC * PH + 8)       // 1032 (+8 slack for dead prefetch)

// J[b][r][c] = target[b][0][r][2047-c]
__global__ void build_J(const float* __restrict__ tgt, float* __restrict__ J) {
  int idx = blockIdx.x * 256 + threadIdx.x;
  if (idx >= NB * H * W) return;
  int c = idx & (W - 1);
  int r = (idx >> 11) & (H - 1);
  int b = idx >> 22;
  J[idx] = tgt[((size_t)(b * H) + r) * W + (W - 1 - c)];
}

// P2[l][i][j][q][p] = psfs[l][j*4+i][q][127-p]
__global__ void build_P2(const float* __restrict__ psfs, float* __restrict__ P2) {
  int idx = blockIdx.x * 256 + threadIdx.x;
  if (idx >= NL * NT * NT * PH * PH) return;
  int p = idx & 127;
  int q = (idx >> 7) & 127;
  int j = (idx >> 14) & 3;
  int i = (idx >> 16) & 3;
  int l = idx >> 18;
  P2[idx] = psfs[((size_t)(l * 16 + j * 4 + i) * PH + q) * PH + (PH - 1 - p)];
}

__global__ __launch_bounds__(256, 2)
void conv_kernel(const float* __restrict__ J, const float* __restrict__ P2,
                 float* __restrict__ out) {
  __shared__ float smem[IMG_OFF + IMG_FLOATS + PSF_FLOATS];
  float* __restrict__ lds  = smem + IMG_OFF;
  float* __restrict__ lpsf = smem + IMG_OFF + IMG_FLOATS;

  const int t  = threadIdx.x;
  const int gx = t >> 3;   // 0..31  -> x = x0 + gx (+32 for .y half)
  const int gy = t & 7;    // 0..7   -> y = y0 + 8*gy + k
  const int x0 = blockIdx.x * TX;
  const int y0 = blockIdx.y * TY;
  const int bl = blockIdx.z;
  const int b  = bl / NL;
  const int l  = bl - b * NL;
  const float* __restrict__ Jb = J + (size_t)b * H * W;

  const int tylo = (y0 > OV2 ? (y0 - OV2) : 0) / HS;
  const int tyhi = min(NT - 1, (y0 + TY - 1 + OV2) / HS);
  const int txlo = (x0 > OV2 ? (x0 - OV2) : 0) / HS;
  const int txhi = min(NT - 1, (x0 + TX - 1 + OV2) / HS);

  v2 facc[8] = {};
  v2 nacc[8] = {};

  for (int ti = tylo; ti <= tyhi; ++ti) {
    const int h0 = max(0, ti * HS - OV2);
    const int h1 = min(H, (ti + 1) * HS + OV2);
    for (int tj = txlo; tj <= txhi; ++tj) {
      const int w0 = max(0, tj * HS - OV2);
      const int w1 = min(W, (tj + 1) * HS + OV2);
      const float* __restrict__ Pb = P2 + (size_t)((l * NT + ti) * NT + tj) * (PH * PH);

      v2 acc[8] = {};

      #pragma unroll 1
      for (int qc = 0; qc < PH; qc += QC) {
        __syncthreads();
        // stage J rows r = x + 64 - q  (zero outside the tile rect)
        const int rbase = x0 + PC - qc - (QC - 1);
        const int cbase = y0 - (PC - 1);
        for (int rr = (t >> 6); rr < RROWS; rr += 4) {
          const int rg = rbase + rr;
          const bool rok = (rg >= w0) && (rg < w1);
          const float* __restrict__ Jrow = Jb + (size_t)rg * W;
          for (int cc = (t & 63); cc < CCOLS; cc += 64) {
            const int cg = cbase + cc;
            float v = 0.0f;
            if (rok && cg >= h0 && cg < h1) v = Jrow[cg];
            lds[rr * LSTRIDE + cc + 2] = v;   // +2 col shift: even window bases
          }
        }
        // stage psf chunk (QC rows of 128)
        for (int i = t; i < QC * PH; i += 256) lpsf[i] = Pb[qc * PH + i];
        __syncthreads();

        #pragma unroll 1
        for (int q = 0; q < QC; ++q) {
          const float* __restrict__ pr = lpsf + q * PH;   // wave-uniform -> broadcast
          const int r0 = (gx + (QC - 1 - q)) * LSTRIDE;
          const int r1 = r0 + 32 * LSTRIDE;
          const int cb = (gy << 3) + 2 * PC + 1;          // 8gy+129 (odd)

          // window w[j] <-> col cb - 8g + 7 - j  (15 live entries)
          v2 w[15];
          #pragma unroll
          for (int j = 0; j < 15; ++j) {
            const int c = cb + 7 - j;                     // cb+7 .. cb-7 (even base cb-7)
            w[j] = (v2){ lds[r0 + c], lds[r1 + c] };
          }
          float ps[8];
          #pragma unroll
          for (int i = 0; i < 8; ++i) ps[i] = pr[i];

          #pragma unroll 2
          for (int g = 0; g < 16; ++g) {
            // prefetch next group's 8 cols [cb-8g-15, cb-8g-8] (even base) + psf row chunk
            v2 nw[8];
            float psn[8];
            const int cpf = cb - 8 * g - 15;
            #pragma unroll
            for (int i2 = 0; i2 < 8; ++i2) {
              const int c = cpf + i2;
              nw[7 - i2] = (v2){ lds[r0 + c], lds[r1 + c] };
              psn[i2] = pr[8 * g + 8 + i2];
            }
            // compute 8 p-steps on the current window
            #pragma unroll
            for (int s = 0; s < 8; ++s) {
              const v2 s2 = { ps[s], ps[s] };
              #pragma unroll
              for (int k = 0; k < 8; ++k)
                acc[k] = __builtin_elementwise_fma(s2, w[s + 7 - k], acc[k]);
            }
            // rotate window
            #pragma unroll
            for (int j = 0; j < 7; ++j) w[j] = w[j + 8];
            #pragma unroll
            for (int i = 0; i < 8; ++i) w[7 + i] = nw[i];
            #pragma unroll
            for (int i = 0; i < 8; ++i) ps[i] = psn[i];
          }
        }
      }

      // window weights + accumulate
      const int Sh = h1 - h0, Sw = w1 - w0;
      const float sig = 0.25f * (float)min(Sh, Sw);
      const float c2 = 0.5f / (sig * sig);
      const float stepy = (float)Sh / (float)(Sh - 1);
      const float stepx = (float)Sw / (float)(Sw - 1);
      v2 wx2;
      {
        const int xa = x0 + gx, xb = x0 + gx + 32;
        const float xva = -0.5f * (float)Sw + (float)(xa - w0) * stepx;
        const float xvb = -0.5f * (float)Sw + (float)(xb - w0) * stepx;
        wx2.x = (xa >= w0 && xa < w1) ? __expf(-xva * xva * c2) : 0.0f;
        wx2.y = (xb >= w0 && xb < w1) ? __expf(-xvb * xvb * c2) : 0.0f;
      }
      #pragma unroll
      for (int k = 0; k < 8; ++k) {
        const int y = y0 + (gy << 3) + k;
        const float yv = -0.5f * (float)Sh + (float)(y - h0) * stepy;
        const float wyk = (y >= h0 && y < h1) ? __expf(-yv * yv * c2) : 0.0f;
        const v2 wf = { wyk * wx2.x, wyk * wx2.y };
        facc[k] = __builtin_elementwise_fma(wf, acc[k], facc[k]);
        nacc[k] += wf;
      }
    }
  }

  // rotated store: final[b,l, x, 2047-y]
  #pragma unroll
  for (int m = 0; m < 2; ++m) {
    const int x = x0 + gx + 32 * m;
    float* __restrict__ orow = out + ((size_t)(b * NL + l) * H + x) * W;
    #pragma unroll
    for (int k = 0; k < 8; ++k) {
      const int y = y0 + (gy << 3) + k;
      const float f = m ? facc[k].y : facc[k].x;
      const float n = m ? nacc[k].y : nacc[k].x;
      orow[W - 1 - y] = f / fmaxf(n, 1e-12f);
    }
  }
}

extern "C" void kernel_launch(void* const* d_in, const int* in_sizes, int n_in,
                              void* d_out, int out_size, void* d_ws, size_t ws_size,
                              hipStream_t stream) {
  const float* tgt  = (const float*)d_in[0];
  const float* psfs = (const float*)d_in[1];
  float* J  = (float*)d_ws;                    // NB*H*W floats (33.5 MB)
  float* P2 = J + (size_t)NB * H * W;          // 3*16*128*128 floats (3.1 MB)
  float* o  = (float*)d_out;

  build_J<<<dim3((NB * H * W + 255) / 256), dim3(256), 0, stream>>>(tgt, J);
  build_P2<<<dim3((NL * NT * NT * PH * PH + 255) / 256), dim3(256), 0, stream>>>(psfs, P2);
  conv_kernel<<<dim3(W / TX, H / TY, NB * NL), dim3(256), 0, stream>>>(J, P2, o);
}

// Round 3
// 4240.173 us; speedup vs baseline: 9.1675x; 6.0416x over previous
//
#include <hip/hip_runtime.h>

typedef __attribute__((ext_vector_type(8))) short short8;
typedef __attribute__((ext_vector_type(4))) float f32x4;

#define IMH 2048
#define IMW 2048
#define NB 2
#define NL 3
#define NT 4
#define HS 512
#define OV2 32
#define PH 128

#define PSTRIDE 200           // LDS patch col stride (elems): step 100 words -> 2-way only
#define PATCH_ROWS 128
#define NDI 10                // distinct B fragments per q

__device__ __forceinline__ ushort f2bf(float f) {
  unsigned u = __float_as_uint(f);
  return (ushort)((u + 0x7FFFu + ((u >> 16) & 1u)) >> 16);
}

// J16[b][r][c] = bf16(target[b][0][r][2047-c])
__global__ void build_J16(const float* __restrict__ tgt, ushort* __restrict__ J16) {
  int idx = blockIdx.x * 256 + threadIdx.x;
  if (idx >= NB * IMH * IMW) return;
  int c = idx & (IMW - 1);
  int r = (idx >> 11) & (IMH - 1);
  int b = idx >> 22;
  J16[idx] = f2bf(tgt[((size_t)(b * IMH) + r) * IMW + (IMW - 1 - c)]);
}

// B fragments in MFMA register order.
// Bfrag[pf][q][di][lane] (short8): lane: n=lane&15, h=lane>>4; elem i -> k=8h+i;
// value = psf_rot[p, q] with p = 16*di + n - 8h - i, psf_rot[p,q] = psfs[l][tj*4+ti][q][127-p]
// pf = (l*4 + ti)*4 + tj
__global__ void build_Bfrag(const float* __restrict__ psfs, uint4* __restrict__ Bf) {
  int idx = blockIdx.x * 256 + threadIdx.x;
  if (idx >= 48 * 128 * NDI * 64) return;
  int ln = idx & 63;
  int di = (idx >> 6) % NDI;
  int q  = (idx / (64 * NDI)) & 127;
  int pf = idx / (64 * NDI * 128);
  int tj = pf & 3, ti = (pf >> 2) & 3, l = pf >> 4;
  const float* col = psfs + ((size_t)((l * 16 + tj * 4 + ti) * PH + q)) * PH;
  int n = ln & 15, h = ln >> 4;
  int p0 = 16 * di + n - 8 * h;
  ushort v[8];
  #pragma unroll
  for (int i = 0; i < 8; ++i) {
    int p = p0 - i;
    v[i] = (p >= 0 && p < PH) ? f2bf(col[PH - 1 - p]) : (ushort)0;
  }
  uint4 o;
  o.x = (unsigned)v[0] | ((unsigned)v[1] << 16);
  o.y = (unsigned)v[2] | ((unsigned)v[3] << 16);
  o.z = (unsigned)v[4] | ((unsigned)v[5] << 16);
  o.w = (unsigned)v[6] | ((unsigned)v[7] << 16);
  Bf[idx] = o;
}

__global__ __launch_bounds__(256, 2)
void conv_mfma(const ushort* __restrict__ J16, const short8* __restrict__ Bfrag,
               float* __restrict__ out) {
  __shared__ __align__(16) ushort patch[PATCH_ROWS * PSTRIDE];   // 51200 B

  const int tid  = threadIdx.x;
  const int lane = tid & 63;
  const int xs   = tid >> 6;      // wave id = x-subtile
  const int n    = lane & 15;
  const int hq   = lane >> 4;

  // 8x8 patch-group swizzle for L2 locality on B fragments
  const int f = blockIdx.x + (blockIdx.y << 5);
  const int g = f >> 6, wi = f & 63;
  const int x0 = ((((g & 3) << 3) + (wi & 7)) << 6);
  const int y0 = ((((g >> 2) << 3) + (wi >> 3)) << 6);
  const int bl = blockIdx.z;
  const int b = bl / NL, l = bl - NL * b;

  const int tylo = (y0 > OV2 ? (y0 - OV2) : 0) / HS;
  const int tyhi = min(NT - 1, (y0 + 63 + OV2) / HS);
  const int txlo = (x0 > OV2 ? (x0 - OV2) : 0) / HS;
  const int txhi = min(NT - 1, (x0 + 63 + OV2) / HS);

  f32x4 facc[4] = {};
  f32x4 nacc[4] = {};

  for (int ti = tylo; ti <= tyhi; ++ti) {
    const int h0 = max(0, ti * HS - OV2);
    const int h1 = min(IMH, (ti + 1) * HS + OV2);
    for (int tj = txlo; tj <= txhi; ++tj) {
      const int w0 = max(0, tj * HS - OV2);
      const int w1 = min(IMW, (tj + 1) * HS + OV2);

      const short8* __restrict__ Bt =
          Bfrag + (size_t)((l * 4 + ti) * 4 + tj) * (128 * NDI * 64) + lane;

      f32x4 acc[4] = {};

      #pragma unroll 1
      for (int qlo = 0; qlo < 128; qlo += 64) {
        const int rrlo = 65 - qlo;     // 65 (q<64) or 1 (q>=64)
        __syncthreads();
        // stage 127 rows x 192 cols of the (clipped) J patch as bf16
        for (int slot = tid >> 6; slot < 127; slot += 4) {
          const int rg = x0 - 64 + rrlo + slot;
          const bool rok = (rg >= w0) && (rg < w1);
          const ushort* __restrict__ Jrow =
              J16 + ((size_t)b << 22) + ((size_t)rg << 11);
          #pragma unroll
          for (int cch = 0; cch < 3; ++cch) {
            const int cc = (tid & 63) + (cch << 6);
            const int tg = y0 - 64 + cc;
            ushort v = 0;
            if (rok && tg >= h0 && tg < h1) v = Jrow[tg];
            patch[slot * PSTRIDE + cc] = v;
          }
        }
        __syncthreads();

        const int sbase = (xs << 4) + n + 128 - rrlo;

        short8 B0[NDI], B1[NDI];
        {
          const short8* __restrict__ Bp = Bt + (size_t)qlo * (NDI * 64);
          #pragma unroll
          for (int d = 0; d < NDI; ++d) B0[d] = Bp[d << 6];
        }

        auto qstep = [&](int q, short8* Bc, short8* Bn, int qn) {
          // prefetch next q's B fragments
          const short8* __restrict__ Bp = Bt + (size_t)qn * (NDI * 64);
          #pragma unroll
          for (int d = 0; d < NDI; ++d) Bn[d] = Bp[d << 6];
          // A fragments: 6 k-chunks from LDS
          const ushort* __restrict__ ar =
              patch + (sbase - q) * PSTRIDE + (hq << 3);
          short8 A0 = *(const short8*)(ar);
          short8 A1 = *(const short8*)(ar + 32);
          short8 A2 = *(const short8*)(ar + 64);
          short8 A3 = *(const short8*)(ar + 96);
          short8 A4 = *(const short8*)(ar + 128);
          short8 A5 = *(const short8*)(ar + 160);
          // active (s, j) pairs; B index di = 8 + s - 2j
          acc[0] = __builtin_amdgcn_mfma_f32_16x16x32_bf16(A0, Bc[8], acc[0], 0, 0, 0);
          acc[1] = __builtin_amdgcn_mfma_f32_16x16x32_bf16(A0, Bc[9], acc[1], 0, 0, 0);
          acc[0] = __builtin_amdgcn_mfma_f32_16x16x32_bf16(A1, Bc[6], acc[0], 0, 0, 0);
          acc[1] = __builtin_amdgcn_mfma_f32_16x16x32_bf16(A1, Bc[7], acc[1], 0, 0, 0);
          acc[2] = __builtin_amdgcn_mfma_f32_16x16x32_bf16(A1, Bc[8], acc[2], 0, 0, 0);
          acc[3] = __builtin_amdgcn_mfma_f32_16x16x32_bf16(A1, Bc[9], acc[3], 0, 0, 0);
          acc[0] = __builtin_amdgcn_mfma_f32_16x16x32_bf16(A2, Bc[4], acc[0], 0, 0, 0);
          acc[1] = __builtin_amdgcn_mfma_f32_16x16x32_bf16(A2, Bc[5], acc[1], 0, 0, 0);
          acc[2] = __builtin_amdgcn_mfma_f32_16x16x32_bf16(A2, Bc[6], acc[2], 0, 0, 0);
          acc[3] = __builtin_amdgcn_mfma_f32_16x16x32_bf16(A2, Bc[7], acc[3], 0, 0, 0);
          acc[0] = __builtin_amdgcn_mfma_f32_16x16x32_bf16(A3, Bc[2], acc[0], 0, 0, 0);
          acc[1] = __builtin_amdgcn_mfma_f32_16x16x32_bf16(A3, Bc[3], acc[1], 0, 0, 0);
          acc[2] = __builtin_amdgcn_mfma_f32_16x16x32_bf16(A3, Bc[4], acc[2], 0, 0, 0);
          acc[3] = __builtin_amdgcn_mfma_f32_16x16x32_bf16(A3, Bc[5], acc[3], 0, 0, 0);
          acc[0] = __builtin_amdgcn_mfma_f32_16x16x32_bf16(A4, Bc[0], acc[0], 0, 0, 0);
          acc[1] = __builtin_amdgcn_mfma_f32_16x16x32_bf16(A4, Bc[1], acc[1], 0, 0, 0);
          acc[2] = __builtin_amdgcn_mfma_f32_16x16x32_bf16(A4, Bc[2], acc[2], 0, 0, 0);
          acc[3] = __builtin_amdgcn_mfma_f32_16x16x32_bf16(A4, Bc[3], acc[3], 0, 0, 0);
          acc[2] = __builtin_amdgcn_mfma_f32_16x16x32_bf16(A5, Bc[0], acc[2], 0, 0, 0);
          acc[3] = __builtin_amdgcn_mfma_f32_16x16x32_bf16(A5, Bc[1], acc[3], 0, 0, 0);
        };

        #pragma unroll 1
        for (int q2 = 0; q2 < 64; q2 += 2) {
          const int q = qlo + q2;
          qstep(q, B0, B1, q + 1);
          qstep(q + 1, B1, B0, min(q + 2, 127));
        }
      }

      // window weights for this tile
      const int Sh = h1 - h0, Sw = w1 - w0;
      const float sig = 0.25f * (float)min(Sh, Sw);
      const float c2 = 0.5f / (sig * sig);
      const float stepy = (float)Sh / (float)(Sh - 1);
      const float stepx = (float)Sw / (float)(Sw - 1);
      float wx[4];
      #pragma unroll
      for (int r = 0; r < 4; ++r) {
        const int x = x0 + (xs << 4) + (hq << 2) + r;
        const float xv = -0.5f * (float)Sw + (float)(x - w0) * stepx;
        wx[r] = (x >= w0 && x < w1) ? __expf(-xv * xv * c2) : 0.0f;
      }
      #pragma unroll
      for (int s = 0; s < 4; ++s) {
        const int y = y0 + (s << 4) + n;
        const float yv = -0.5f * (float)Sh + (float)(y - h0) * stepy;
        const float wy = (y >= h0 && y < h1) ? __expf(-yv * yv * c2) : 0.0f;
        #pragma unroll
        for (int r = 0; r < 4; ++r) {
          const float wf = wy * wx[r];
          facc[s][r] += wf * acc[s][r];
          nacc[s][r] += wf;
        }
      }
    }
  }

  // store: out[b, l, x, 2047 - y]
  #pragma unroll
  for (int s = 0; s < 4; ++s) {
    const int y = y0 + (s << 4) + n;
    #pragma unroll
    for (int r = 0; r < 4; ++r) {
      const int x = x0 + (xs << 4) + (hq << 2) + r;
      out[(((size_t)(b * NL + l) << 11) + x) * IMW + (IMW - 1 - y)] =
          facc[s][r] / fmaxf(nacc[s][r], 1e-12f);
    }
  }
}

extern "C" void kernel_launch(void* const* d_in, const int* in_sizes, int n_in,
                              void* d_out, int out_size, void* d_ws, size_t ws_size,
                              hipStream_t stream) {
  const float* tgt  = (const float*)d_in[0];
  const float* psfs = (const float*)d_in[1];
  ushort* J16 = (ushort*)d_ws;                                  // 16.8 MB
  short8* Bf  = (short8*)((char*)d_ws + (size_t)NB * IMH * IMW * 2); // 62.9 MB
  float* o = (float*)d_out;

  build_J16<<<dim3((NB * IMH * IMW + 255) / 256), 256, 0, stream>>>(tgt, J16);
  build_Bfrag<<<dim3((48 * 128 * NDI * 64 + 255) / 256), 256, 0, stream>>>(
      psfs, (uint4*)Bf);
  conv_mfma<<<dim3(32, 32, NB * NL), 256, 0, stream>>>(J16, Bf, o);
}

// Round 4
// 2617.111 us; speedup vs baseline: 14.8529x; 1.6202x over previous
//
#include <hip/hip_runtime.h>

typedef __attribute__((ext_vector_type(8))) short short8;
typedef __attribute__((ext_vector_type(4))) float f32x4;

#define IMH 2048
#define IMW 2048
#define NB 2
#define NL 3
#define NT 4
#define HS 512
#define OV2 32
#define PH 128

#define PSTRIDE 208           // ushorts per LDS row: 416 B, 16B-aligned rows
#define PATCH_ROWS 128        // 128*208*2 = 53248 B -> 3 blocks/CU
#define NDI 10                // distinct B fragments per q

__device__ __forceinline__ ushort f2bf(float f) {
  unsigned u = __float_as_uint(f);
  return (ushort)((u + 0x7FFFu + ((u >> 16) & 1u)) >> 16);
}

// J16[b][r][c] = bf16(target[b][0][r][2047-c])
__global__ void build_J16(const float* __restrict__ tgt, ushort* __restrict__ J16) {
  int idx = blockIdx.x * 256 + threadIdx.x;
  if (idx >= NB * IMH * IMW) return;
  int c = idx & (IMW - 1);
  int r = (idx >> 11) & (IMH - 1);
  int b = idx >> 22;
  J16[idx] = f2bf(tgt[((size_t)(b * IMH) + r) * IMW + (IMW - 1 - c)]);
}

// Bfrag[pf][q][di][lane] (short8): n=lane&15, h=lane>>4; elem i -> k=8h+i;
// value = psf_rot[p,q], p = 16*di + n - 8h - i; psf_rot[p,q] = psfs[l][tj*4+ti][q][127-p]
__global__ void build_Bfrag(const float* __restrict__ psfs, uint4* __restrict__ Bf) {
  int idx = blockIdx.x * 256 + threadIdx.x;
  if (idx >= 48 * 128 * NDI * 64) return;
  int ln = idx & 63;
  int di = (idx >> 6) % NDI;
  int q  = (idx / (64 * NDI)) & 127;
  int pf = idx / (64 * NDI * 128);
  int tj = pf & 3, ti = (pf >> 2) & 3, l = pf >> 4;
  const float* col = psfs + ((size_t)((l * 16 + tj * 4 + ti) * PH + q)) * PH;
  int n = ln & 15, h = ln >> 4;
  int p0 = 16 * di + n - 8 * h;
  ushort v[8];
  #pragma unroll
  for (int i = 0; i < 8; ++i) {
    int p = p0 - i;
    v[i] = (p >= 0 && p < PH) ? f2bf(col[PH - 1 - p]) : (ushort)0;
  }
  uint4 o;
  o.x = (unsigned)v[0] | ((unsigned)v[1] << 16);
  o.y = (unsigned)v[2] | ((unsigned)v[3] << 16);
  o.z = (unsigned)v[4] | ((unsigned)v[5] << 16);
  o.w = (unsigned)v[6] | ((unsigned)v[7] << 16);
  Bf[idx] = o;
}

__global__ __launch_bounds__(256, 3)
void conv_mfma(const ushort* __restrict__ J16, const short8* __restrict__ Bfrag,
               float* __restrict__ out) {
  __shared__ __align__(16) ushort patch[PATCH_ROWS * PSTRIDE];   // 53248 B

  const int tid  = threadIdx.x;
  const int lane = tid & 63;
  const int xs   = tid >> 6;      // wave id = x-subtile
  const int n    = lane & 15;
  const int hq   = lane >> 4;

  // 8x8 patch-group swizzle for B-fragment L2 locality
  const int f = blockIdx.x + (blockIdx.y << 5);
  const int g = f >> 6, wi = f & 63;
  const int x0 = ((((g & 3) << 3) + (wi & 7)) << 6);
  const int y0 = ((((g >> 2) << 3) + (wi >> 3)) << 6);
  const int bl = blockIdx.z;
  const int b = bl / NL, l = bl - NL * b;

  const int tylo = (y0 > OV2 ? (y0 - OV2) : 0) / HS;
  const int tyhi = min(NT - 1, (y0 + 63 + OV2) / HS);
  const int txlo = (x0 > OV2 ? (x0 - OV2) : 0) / HS;
  const int txhi = min(NT - 1, (x0 + 63 + OV2) / HS);

  f32x4 facc[4] = {};

  for (int ti = tylo; ti <= tyhi; ++ti) {
    const int h0 = max(0, ti * HS - OV2);
    const int h1 = min(IMH, (ti + 1) * HS + OV2);
    for (int tj = txlo; tj <= txhi; ++tj) {
      const int w0 = max(0, tj * HS - OV2);
      const int w1 = min(IMW, (tj + 1) * HS + OV2);

      const short8* __restrict__ Bt =
          Bfrag + (size_t)((l * 4 + ti) * 4 + tj) * (128 * NDI * 64) + lane;

      f32x4 acc[4] = {};

      #pragma unroll 1
      for (int qlo = 0; qlo < 128; qlo += 64) {
        const int rrlo = 65 - qlo;     // 65 (q<64) or 1 (q>=64)
        __syncthreads();
        // stage 127 rows x 24 16B-chunks; chunk-granular clip; XOR swizzle
        const int rbase = x0 - 64 + rrlo;
        const int cbase = y0 - 64;
        #pragma unroll 1
        for (int item = tid; item < 127 * 24; item += 256) {
          const int slot = item / 24;
          const int c    = item - slot * 24;
          const int rg   = rbase + slot;
          const int cg   = cbase + (c << 3);
          uint4 v = {0u, 0u, 0u, 0u};
          if (rg >= w0 && rg < w1 && cg >= h0 && (cg + 8) <= h1)
            v = *(const uint4*)(J16 + ((size_t)b << 22) + ((size_t)rg << 11) + cg);
          *(uint4*)&patch[slot * PSTRIDE + (((c ^ (slot & 3))) << 3)] = v;
        }
        __syncthreads();

        const int sbase = (xs << 4) + n + 128 - rrlo;

        short8 B0[NDI], B1[NDI];
        {
          const short8* __restrict__ Bp = Bt + (size_t)qlo * (NDI * 64);
          #pragma unroll
          for (int d = 0; d < NDI; ++d) B0[d] = Bp[d << 6];
        }

        auto qstep = [&](int q, short8* Bc, short8* Bn, int qn) {
          // issue next q's B loads (kept live across sched_barrier -> true prefetch)
          const short8* __restrict__ Bp = Bt + (size_t)qn * (NDI * 64);
          #pragma unroll
          for (int d = 0; d < NDI; ++d) Bn[d] = Bp[d << 6];
          // A fragments from LDS (swizzled chunks)
          const int row = sbase - q;
          const ushort* __restrict__ ar =
              patch + row * PSTRIDE + ((hq ^ (row & 3)) << 3);
          short8 A0 = *(const short8*)(ar);
          short8 A1 = *(const short8*)(ar + 32);
          short8 A2 = *(const short8*)(ar + 64);
          short8 A3 = *(const short8*)(ar + 96);
          short8 A4 = *(const short8*)(ar + 128);
          short8 A5 = *(const short8*)(ar + 160);
          __builtin_amdgcn_sched_barrier(0);   // loads stay above, MFMAs below
          // active (s, j) pairs; B index di = 8 + s - 2j
          acc[0] = __builtin_amdgcn_mfma_f32_16x16x32_bf16(A0, Bc[8], acc[0], 0, 0, 0);
          acc[1] = __builtin_amdgcn_mfma_f32_16x16x32_bf16(A0, Bc[9], acc[1], 0, 0, 0);
          acc[0] = __builtin_amdgcn_mfma_f32_16x16x32_bf16(A1, Bc[6], acc[0], 0, 0, 0);
          acc[1] = __builtin_amdgcn_mfma_f32_16x16x32_bf16(A1, Bc[7], acc[1], 0, 0, 0);
          acc[2] = __builtin_amdgcn_mfma_f32_16x16x32_bf16(A1, Bc[8], acc[2], 0, 0, 0);
          acc[3] = __builtin_amdgcn_mfma_f32_16x16x32_bf16(A1, Bc[9], acc[3], 0, 0, 0);
          acc[0] = __builtin_amdgcn_mfma_f32_16x16x32_bf16(A2, Bc[4], acc[0], 0, 0, 0);
          acc[1] = __builtin_amdgcn_mfma_f32_16x16x32_bf16(A2, Bc[5], acc[1], 0, 0, 0);
          acc[2] = __builtin_amdgcn_mfma_f32_16x16x32_bf16(A2, Bc[6], acc[2], 0, 0, 0);
          acc[3] = __builtin_amdgcn_mfma_f32_16x16x32_bf16(A2, Bc[7], acc[3], 0, 0, 0);
          acc[0] = __builtin_amdgcn_mfma_f32_16x16x32_bf16(A3, Bc[2], acc[0], 0, 0, 0);
          acc[1] = __builtin_amdgcn_mfma_f32_16x16x32_bf16(A3, Bc[3], acc[1], 0, 0, 0);
          acc[2] = __builtin_amdgcn_mfma_f32_16x16x32_bf16(A3, Bc[4], acc[2], 0, 0, 0);
          acc[3] = __builtin_amdgcn_mfma_f32_16x16x32_bf16(A3, Bc[5], acc[3], 0, 0, 0);
          acc[0] = __builtin_amdgcn_mfma_f32_16x16x32_bf16(A4, Bc[0], acc[0], 0, 0, 0);
          acc[1] = __builtin_amdgcn_mfma_f32_16x16x32_bf16(A4, Bc[1], acc[1], 0, 0, 0);
          acc[2] = __builtin_amdgcn_mfma_f32_16x16x32_bf16(A4, Bc[2], acc[2], 0, 0, 0);
          acc[3] = __builtin_amdgcn_mfma_f32_16x16x32_bf16(A4, Bc[3], acc[3], 0, 0, 0);
          acc[2] = __builtin_amdgcn_mfma_f32_16x16x32_bf16(A5, Bc[0], acc[2], 0, 0, 0);
          acc[3] = __builtin_amdgcn_mfma_f32_16x16x32_bf16(A5, Bc[1], acc[3], 0, 0, 0);
        };

        #pragma unroll 1
        for (int q2 = 0; q2 < 64; q2 += 2) {
          const int q = qlo + q2;
          qstep(q, B0, B1, q + 1);
          qstep(q + 1, B1, B0, min(q + 2, 127));
        }
      }

      // apply window for this tile (acc -> facc); norm recomputed in epilogue
      const int Sh = h1 - h0, Sw = w1 - w0;
      const float sig = 0.25f * (float)min(Sh, Sw);
      const float c2 = 0.5f / (sig * sig);
      const float stepy = (float)Sh / (float)(Sh - 1);
      const float stepx = (float)Sw / (float)(Sw - 1);
      float wx[4];
      #pragma unroll
      for (int r = 0; r < 4; ++r) {
        const int x = x0 + (xs << 4) + (hq << 2) + r;
        const float xv = -0.5f * (float)Sw + (float)(x - w0) * stepx;
        wx[r] = (x >= w0 && x < w1) ? __expf(-xv * xv * c2) : 0.0f;
      }
      #pragma unroll
      for (int s = 0; s < 4; ++s) {
        const int y = y0 + (s << 4) + n;
        const float yv = -0.5f * (float)Sh + (float)(y - h0) * stepy;
        const float wy = (y >= h0 && y < h1) ? __expf(-yv * yv * c2) : 0.0f;
        #pragma unroll
        for (int r = 0; r < 4; ++r) facc[s][r] += wy * wx[r] * acc[s][r];
      }
    }
  }

  // epilogue: recompute norm analytically, store out[b,l,x,2047-y]
  f32x4 nacc[4] = {};
  for (int ti = tylo; ti <= tyhi; ++ti) {
    const int h0 = max(0, ti * HS - OV2);
    const int h1 = min(IMH, (ti + 1) * HS + OV2);
    for (int tj = txlo; tj <= txhi; ++tj) {
      const int w0 = max(0, tj * HS - OV2);
      const int w1 = min(IMW, (tj + 1) * HS + OV2);
      const int Sh = h1 - h0, Sw = w1 - w0;
      const float sig = 0.25f * (float)min(Sh, Sw);
      const float c2 = 0.5f / (sig * sig);
      const float stepy = (float)Sh / (float)(Sh - 1);
      const float stepx = (float)Sw / (float)(Sw - 1);
      float wx[4];
      #pragma unroll
      for (int r = 0; r < 4; ++r) {
        const int x = x0 + (xs << 4) + (hq << 2) + r;
        const float xv = -0.5f * (float)Sw + (float)(x - w0) * stepx;
        wx[r] = (x >= w0 && x < w1) ? __expf(-xv * xv * c2) : 0.0f;
      }
      #pragma unroll
      for (int s = 0; s < 4; ++s) {
        const int y = y0 + (s << 4) + n;
        const float yv = -0.5f * (float)Sh + (float)(y - h0) * stepy;
        const float wy = (y >= h0 && y < h1) ? __expf(-yv * yv * c2) : 0.0f;
        #pragma unroll
        for (int r = 0; r < 4; ++r) nacc[s][r] += wy * wx[r];
      }
    }
  }
  #pragma unroll
  for (int s = 0; s < 4; ++s) {
    const int y = y0 + (s << 4) + n;
    #pragma unroll
    for (int r = 0; r < 4; ++r) {
      const int x = x0 + (xs << 4) + (hq << 2) + r;
      out[(((size_t)(b * NL + l) << 11) + x) * IMW + (IMW - 1 - y)] =
          facc[s][r] / fmaxf(nacc[s][r], 1e-12f);
    }
  }
}

extern "C" void kernel_launch(void* const* d_in, const int* in_sizes, int n_in,
                              void* d_out, int out_size, void* d_ws, size_t ws_size,
                              hipStream_t stream) {
  const float* tgt  = (const float*)d_in[0];
  const float* psfs = (const float*)d_in[1];
  ushort* J16 = (ushort*)d_ws;                                       // 16.8 MB
  short8* Bf  = (short8*)((char*)d_ws + (size_t)NB * IMH * IMW * 2); // 62.9 MB
  float* o = (float*)d_out;

  build_J16<<<dim3((NB * IMH * IMW + 255) / 256), 256, 0, stream>>>(tgt, J16);
  build_Bfrag<<<dim3((48 * 128 * NDI * 64 + 255) / 256), 256, 0, stream>>>(
      psfs, (uint4*)Bf);
  conv_mfma<<<dim3(32, 32, NB * NL), 256, 0, stream>>>(J16, Bf, o);
}